// Round 6
// baseline (315.266 us; speedup 1.0000x reference)
//
#include <hip/hip_runtime.h>
#include <stdint.h>

#define T_STEPS 2048
#define B_CH    8192
#define DT_F    0.01f
#define NCHUNK  32
#define CHUNK   (T_STEPS / NCHUNK)   // 64 accumulated steps per chunk
#define WARM    64                   // warm-up steps (validated: absmax 0.0 at R3/R4)
#define TILE    4                    // timesteps per LDS buffer
#define NBUF    3                    // triple buffer -> prefetch distance 2 tiles

__device__ __forceinline__ float fast_rsqrt(float x) { return __builtin_amdgcn_rsqf(x); }
__device__ __forceinline__ float fast_log2(float x)  { return __builtin_amdgcn_logf(x); }

struct Q9 { float q00,q01,q02,q10,q11,q12,q20,q21,q22; };

// EXACT reference GS step (rows normalized every step). Only the log is
// deferred: P_k *= n_k per step, harvested every 16 steps (P in [0.04,1]).
__device__ __forceinline__ void gs_step(float x, float y, float z, Q9& Q,
                                        float& P0, float& P1, float& P2) {
  const float a00 = 0.9f;            // 1 - DT*SIGMA
  const float a01 = 0.1f;            // DT*SIGMA
  const float a11 = 0.99f;           // 1 - DT
  const float a22 = 1.0f - DT_F * (8.0f / 3.0f);
  float a10 = DT_F * (28.0f - z);
  float a12 = -DT_F * x;
  float a20 = DT_F * y;
  float a21 = DT_F * x;

  float m00 = a00*Q.q00 + a01*Q.q10;
  float m01 = a00*Q.q01 + a01*Q.q11;
  float m02 = a00*Q.q02 + a01*Q.q12;
  float m10 = a10*Q.q00 + a11*Q.q10 + a12*Q.q20;
  float m11 = a10*Q.q01 + a11*Q.q11 + a12*Q.q21;
  float m12 = a10*Q.q02 + a11*Q.q12 + a12*Q.q22;
  float m20 = a20*Q.q00 + a21*Q.q10 + a22*Q.q20;
  float m21 = a20*Q.q01 + a21*Q.q11 + a22*Q.q21;
  float m22 = a20*Q.q02 + a21*Q.q12 + a22*Q.q22;

  float n0 = m00*m00 + m01*m01 + m02*m02;
  float d1 = m00*m10 + m01*m11 + m02*m12;
  float d2 = m00*m20 + m01*m21 + m02*m22;

  float i0 = fast_rsqrt(n0);
  float inv0 = i0 * i0;
  P0 *= n0;
  Q.q00 = m00*i0; Q.q01 = m01*i0; Q.q02 = m02*i0;

  float c1 = d1 * inv0;
  float r10 = m10 - c1*m00, r11 = m11 - c1*m01, r12 = m12 - c1*m02;
  float c2 = d2 * inv0;
  float r20 = m20 - c2*m00, r21 = m21 - c2*m01, r22 = m22 - c2*m02;

  float n1 = r10*r10 + r11*r11 + r12*r12;
  float d3 = r10*r20 + r11*r21 + r12*r22;
  float i1 = fast_rsqrt(n1);
  float inv1 = i1 * i1;
  P1 *= n1;
  Q.q10 = r10*i1; Q.q11 = r11*i1; Q.q12 = r12*i1;

  float c3 = d3 * inv1;
  float s20 = r20 - c3*r10, s21 = r21 - c3*r11, s22 = r22 - c3*r12;
  float n2 = s20*s20 + s21*s21 + s22*s22;
  float i2 = fast_rsqrt(n2);
  P2 *= n2;
  Q.q20 = s20*i2; Q.q21 = s21*i2; Q.q22 = s22*i2;
}

// Async-DMA one tile (TILE steps x 3 comps, this wave's 64 chains) into the
// wave-private LDS slice. No destination VGPRs; tracked by this wave's vmcnt.
// g: per-thread pointer (includes chain offset). l: per-thread &slice[0][lane].
__device__ __forceinline__ void dma_tile(const float* __restrict__ g, float* l) {
#pragma unroll
  for (int r = 0; r < TILE * 3; ++r) {
    __builtin_amdgcn_global_load_lds(
        (const __attribute__((address_space(1))) void*)(g + (size_t)r * B_CH),
        (__attribute__((address_space(3))) void*)(l + r * 64),
        4, 0, 0);
  }
}

// Grid: (32, NCHUNK) x 256. One thread per (chain, chunk). Per-wave LDS
// triple-buffer staging via global_load_lds: each wave DMAs only the chains
// it consumes -> no cross-wave LDS deps -> NO barriers, per-wave vmcnt(24)
// waits only (2 newer tiles stay in flight across the wait).
__global__ __launch_bounds__(256) void lyap_chunk_kernel(const float* __restrict__ traj,
                                                         float* __restrict__ ws) {
  __shared__ float lds[NBUF][4][TILE * 3][64];   // 36 KB -> 4 blocks/CU

  const int tid  = threadIdx.x;
  const int w    = tid >> 6;                     // wave in block
  const int lane = tid & 63;
  const int b     = blockIdx.x * 256 + tid;      // chain id
  const int chunk = blockIdx.y;
  const int warm     = (chunk == 0) ? 0 : WARM;
  const int warmTile = warm / TILE;              // 0 or 16 (harvest boundary)
  const int ntiles   = (CHUNK + warm) / TILE;    // 16 or 32
  const float* __restrict__ p =
      traj + (size_t)(chunk * CHUNK - warm) * (3 * B_CH) + b;

  // prime the pipeline: tiles 0..NBUF-1 (ntiles >= 16 > NBUF always)
#pragma unroll
  for (int t = 0; t < NBUF; ++t)
    dma_tile(p + (size_t)t * (TILE * 3 * B_CH), &lds[t][w][0][lane]);

  Q9 Q = {1.f,0.f,0.f, 0.f,1.f,0.f, 0.f,0.f,1.f};
  float S0 = 0.f, S1 = 0.f, S2 = 0.f;
  float B0 = 0.f, B1 = 0.f, B2 = 0.f;
  float P0 = 1.f, P1 = 1.f, P2 = 1.f;

  int slot = 0;
  for (int gt = 0; gt < ntiles; ++gt) {
    if (gt == warmTile) { B0 = S0; B1 = S1; B2 = S2; }  // chunk-start snapshot

    // wait for THIS tile's 12 DMAs; allow the 2 newer tiles (24) in flight.
    asm volatile("s_waitcnt vmcnt(24)" ::: "memory");

    const float* lw = &lds[slot][w][0][lane];
#pragma unroll
    for (int i = 0; i < TILE; ++i) {
      float x = lw[(i * 3 + 0) * 64];
      float y = lw[(i * 3 + 1) * 64];
      float z = lw[(i * 3 + 2) * 64];
      gs_step(x, y, z, Q, P0, P1, P2);
    }

    if ((gt & 3) == 3) {       // harvest deferred logs every 16 steps
      S0 += fast_log2(P0); P0 = 1.f;
      S1 += fast_log2(P1); P1 = 1.f;
      S2 += fast_log2(P2); P2 = 1.f;
    }

    // refill the slot just consumed with tile gt+NBUF (ds_reads above have
    // drained: their results fed this tile's arithmetic).
    asm volatile("" ::: "memory");
    const int ft = gt + NBUF;
    if (ft < ntiles)
      dma_tile(p + (size_t)ft * (TILE * 3 * B_CH), &lds[slot][w][0][lane]);

    slot = (slot + 1 == NBUF) ? 0 : slot + 1;
  }

  ws[(chunk * 3 + 0) * B_CH + b] = S0 - B0;
  ws[(chunk * 3 + 1) * B_CH + b] = S1 - B1;
  ws[(chunk * 3 + 2) * B_CH + b] = S2 - B2;
}

__global__ __launch_bounds__(256) void lyap_reduce_kernel(const float* __restrict__ ws,
                                                          float* __restrict__ out) {
  const int i = blockIdx.x * 256 + threadIdx.x;  // 0 .. 3*B_CH
  float s = 0.f;
#pragma unroll
  for (int c = 0; c < NCHUNK; ++c) s += ws[c * 3 * B_CH + i];
  const float scale = 0.5f * 0.69314718055994531f / (T_STEPS * DT_F);
  out[i] = s * scale;
}

extern "C" void kernel_launch(void* const* d_in, const int* in_sizes, int n_in,
                              void* d_out, int out_size, void* d_ws, size_t ws_size,
                              hipStream_t stream) {
  (void)in_sizes; (void)n_in; (void)out_size; (void)ws_size;
  const float* traj = (const float*)d_in[0];
  float* out = (float*)d_out;
  float* ws  = (float*)d_ws;   // NCHUNK*3*B_CH*4 = 3.1 MB

  lyap_chunk_kernel<<<dim3(B_CH / 256, NCHUNK), dim3(256), 0, stream>>>(traj, ws);
  lyap_reduce_kernel<<<dim3(3 * B_CH / 256), dim3(256), 0, stream>>>(ws, out);
}

// Round 7
// 295.899 us; speedup vs baseline: 1.0654x; 1.0654x over previous
//
#include <hip/hip_runtime.h>

#define T_STEPS 2048
#define B_CH    8192
#define DT_F    0.01f
#define NCHUNK  64
#define CHUNK   (T_STEPS / NCHUNK)   // 32 accumulated steps per chunk
#define WARM    32                   // warm-up steps; delta^2 ~ 1.4e-4/chunk
#define TILE    4                    // timesteps per register buffer

typedef float v2f __attribute__((ext_vector_type(2)));

__device__ __forceinline__ float fast_rsqrt(float x) { return __builtin_amdgcn_rsqf(x); }
__device__ __forceinline__ float fast_log2(float x)  { return __builtin_amdgcn_logf(x); }
__device__ __forceinline__ v2f v2_rsq(v2f n) {
  v2f r; r.x = fast_rsqrt(n.x); r.y = fast_rsqrt(n.y); return r;
}

struct Q9 { v2f q00,q01,q02,q10,q11,q12,q20,q21,q22; };

// EXACT reference GS step (rows normalized every step), vectorized over 2
// independent chains per lane (packed fp32: <2 x float> -> v_pk_fma_f32).
// Only the log is deferred: P_k *= n_k, harvested every 8 steps (P>=0.2^3).
__device__ __forceinline__ void gs_step(v2f x, v2f y, v2f z, Q9& Q,
                                        v2f& P0, v2f& P1, v2f& P2) {
  const float a00 = 0.9f;            // 1 - DT*SIGMA
  const float a01 = 0.1f;            // DT*SIGMA
  const float a11 = 0.99f;           // 1 - DT
  const float a22 = 1.0f - DT_F * (8.0f / 3.0f);
  v2f a10 = DT_F * (28.0f - z);
  v2f a12 = -DT_F * x;
  v2f a20 = DT_F * y;
  v2f a21 = DT_F * x;

  // M = A * Q  (A[0][2] == 0)
  v2f m00 = a00*Q.q00 + a01*Q.q10;
  v2f m01 = a00*Q.q01 + a01*Q.q11;
  v2f m02 = a00*Q.q02 + a01*Q.q12;
  v2f m10 = a10*Q.q00 + a11*Q.q10 + a12*Q.q20;
  v2f m11 = a10*Q.q01 + a11*Q.q11 + a12*Q.q21;
  v2f m12 = a10*Q.q02 + a11*Q.q12 + a12*Q.q22;
  v2f m20 = a20*Q.q00 + a21*Q.q10 + a22*Q.q20;
  v2f m21 = a20*Q.q01 + a21*Q.q11 + a22*Q.q21;
  v2f m22 = a20*Q.q02 + a21*Q.q12 + a22*Q.q22;

  v2f n0 = m00*m00 + m01*m01 + m02*m02;
  v2f d1 = m00*m10 + m01*m11 + m02*m12;
  v2f d2 = m00*m20 + m01*m21 + m02*m22;

  v2f i0 = v2_rsq(n0);
  v2f inv0 = i0 * i0;
  P0 *= n0;
  Q.q00 = m00*i0; Q.q01 = m01*i0; Q.q02 = m02*i0;

  v2f c1 = d1 * inv0;
  v2f r10 = m10 - c1*m00, r11 = m11 - c1*m01, r12 = m12 - c1*m02;
  v2f c2 = d2 * inv0;
  v2f r20 = m20 - c2*m00, r21 = m21 - c2*m01, r22 = m22 - c2*m02;

  v2f n1 = r10*r10 + r11*r11 + r12*r12;
  v2f d3 = r10*r20 + r11*r21 + r12*r22;
  v2f i1 = v2_rsq(n1);
  v2f inv1 = i1 * i1;
  P1 *= n1;
  Q.q10 = r10*i1; Q.q11 = r11*i1; Q.q12 = r12*i1;

  v2f c3 = d3 * inv1;
  v2f s20 = r20 - c3*r10, s21 = r21 - c3*r11, s22 = r22 - c3*r12;
  v2f n2 = s20*s20 + s21*s21 + s22*s22;
  v2f i2 = v2_rsq(n2);
  P2 *= n2;
  Q.q20 = s20*i2; Q.q21 = s21*i2; Q.q22 = s22*i2;
}

// Grid: (16, NCHUNK) x 256. Each thread owns chains (2c, 2c+1) for one time
// chunk. 1024 blocks -> 4096 waves -> 4 waves/SIMD. Register ping-pong
// staging (staging scheme proven perf-neutral in R3/R4/R5 — issue-bound).
__global__ __launch_bounds__(256) void lyap_chunk_kernel(const float* __restrict__ traj,
                                                         float* __restrict__ ws) {
  const int c = blockIdx.x * 256 + threadIdx.x;      // packed chain-pair id
  const int chunk = blockIdx.y;
  const int warm = (chunk == 0) ? 0 : WARM;
  const int warmPer = warm / (2 * TILE);             // 8-step periods: 0 or 4
  const int nper = (CHUNK + warm) / (2 * TILE);      // 4 or 8
  const int R = B_CH / 2;                            // v2f per component row
  const v2f* __restrict__ p =
      (const v2f*)traj + (size_t)(chunk * CHUNK - warm) * (3 * R) + c;

  v2f sA[TILE][3], sB[TILE][3];
#pragma unroll
  for (int i = 0; i < TILE; ++i) {
    sA[i][0] = p[(i*3 + 0) * R];
    sA[i][1] = p[(i*3 + 1) * R];
    sA[i][2] = p[(i*3 + 2) * R];
  }

  Q9 Q;
  Q.q00 = 1.f; Q.q01 = 0.f; Q.q02 = 0.f;
  Q.q10 = 0.f; Q.q11 = 1.f; Q.q12 = 0.f;
  Q.q20 = 0.f; Q.q21 = 0.f; Q.q22 = 1.f;
  v2f S0 = 0.f, S1 = 0.f, S2 = 0.f;
  v2f B0 = 0.f, B1 = 0.f, B2 = 0.f;
  v2f P0 = 1.f, P1 = 1.f, P2 = 1.f;

  for (int per = 0; per < nper; ++per) {
    // invariant: tile 2*per resident in sA; S fully harvested, P == 1
    if (per == warmPer) { B0 = S0; B1 = S1; B2 = S2; }  // chunk-start snapshot
    {  // prefetch tile 2*per+1 into B (always exists)
      const v2f* pt = p + (size_t)(2*per + 1) * (TILE * 3 * R);
#pragma unroll
      for (int i = 0; i < TILE; ++i) {
        sB[i][0] = pt[(i*3 + 0) * R];
        sB[i][1] = pt[(i*3 + 1) * R];
        sB[i][2] = pt[(i*3 + 2) * R];
      }
    }
#pragma unroll
    for (int i = 0; i < TILE; ++i)
      gs_step(sA[i][0], sA[i][1], sA[i][2], Q, P0, P1, P2);

    if (per + 1 < nper) {  // prefetch tile 2*per+2 into A
      const v2f* pt = p + (size_t)(2*per + 2) * (TILE * 3 * R);
#pragma unroll
      for (int i = 0; i < TILE; ++i) {
        sA[i][0] = pt[(i*3 + 0) * R];
        sA[i][1] = pt[(i*3 + 1) * R];
        sA[i][2] = pt[(i*3 + 2) * R];
      }
    }
#pragma unroll
    for (int i = 0; i < TILE; ++i)
      gs_step(sB[i][0], sB[i][1], sB[i][2], Q, P0, P1, P2);

    // harvest deferred logs (every 8 steps; P0 >= 0.82^8 ~ 0.2)
    S0.x += fast_log2(P0.x); S0.y += fast_log2(P0.y); P0 = 1.f;
    S1.x += fast_log2(P1.x); S1.y += fast_log2(P1.y); P1 = 1.f;
    S2.x += fast_log2(P2.x); S2.y += fast_log2(P2.y); P2 = 1.f;
  }

  v2f* __restrict__ wsv = (v2f*)ws;
  wsv[(chunk*3 + 0) * R + c] = S0 - B0;
  wsv[(chunk*3 + 1) * R + c] = S1 - B1;
  wsv[(chunk*3 + 2) * R + c] = S2 - B2;
}

__global__ __launch_bounds__(256) void lyap_reduce_kernel(const float* __restrict__ ws,
                                                          float* __restrict__ out) {
  const int i = blockIdx.x * 256 + threadIdx.x;      // 0 .. 3*B_CH
  float s = 0.f;
#pragma unroll
  for (int c = 0; c < NCHUNK; ++c) s += ws[c * 3 * B_CH + i];
  const float scale = 0.5f * 0.69314718055994531f / (T_STEPS * DT_F);
  out[i] = s * scale;
}

extern "C" void kernel_launch(void* const* d_in, const int* in_sizes, int n_in,
                              void* d_out, int out_size, void* d_ws, size_t ws_size,
                              hipStream_t stream) {
  (void)in_sizes; (void)n_in; (void)out_size; (void)ws_size;
  const float* traj = (const float*)d_in[0];
  float* out = (float*)d_out;
  float* ws  = (float*)d_ws;   // NCHUNK*3*B_CH*4 = 6.3 MB

  lyap_chunk_kernel<<<dim3(B_CH / 512, NCHUNK), dim3(256), 0, stream>>>(traj, ws);
  lyap_reduce_kernel<<<dim3(3 * B_CH / 256), dim3(256), 0, stream>>>(ws, out);
}